// Round 1
// baseline (1012.878 us; speedup 1.0000x reference)
//
#include <hip/hip_runtime.h>
#include <math.h>

// AngularLayer: out[B,483] = concat(in[B,63], tilts[B,420])
// tilts: for each ordered pair (i<k) of 21 landmarks (x,y at cols 3i,3i+1),
//   v = p_k - p_i (x,y only); tilt = clip(v/||v||, -1, 1), laid out (x,y) per pair.
//
// Memory-bound: 126 MB read + 966 MB write per call -> ~173 us floor @ 6.3 TB/s.
// Strategy: 16 rows/block of 256 threads; stage input via float4 into LDS,
// compute full 16x483 out-tile in LDS, dump via float4 (whole slab contiguous
// and 16B-aligned, so odd stride 483 never touches global-store coalescing).

#define ROWS 16
#define NCOLS 63
#define OUTCOLS 483
#define NPAIRS 210
#define BLOCK 256

__global__ __launch_bounds__(BLOCK) void angular_kernel(
    const float* __restrict__ in, float* __restrict__ out, int B) {
    __shared__ float s_in[ROWS * NCOLS];       // 1008 floats
    __shared__ float s_out[ROWS * OUTCOLS];    // 7728 floats
    __shared__ int   s_pi[NPAIRS];             // 3*i  (x-col of landmark i)
    __shared__ int   s_pk[NPAIRS];             // 3*k

    const int t = threadIdx.x;

    // Build pair->(i,k) column tables once per block (trivial cost).
    if (t < NPAIRS) {
        int p = t, i = 0, off = 0;
        while (off + (20 - i) <= p) { off += 20 - i; ++i; }
        s_pi[t] = 3 * i;
        s_pk[t] = 3 * (i + 1 + (p - off));
    }

    const size_t row0 = (size_t)blockIdx.x * ROWS;
    const bool full = (row0 + ROWS) <= (size_t)B;

    // ---- Stage input slab into LDS ----
    if (full) {
        // Block slab = 1008 floats starting at byte offset blockIdx*4032 (16B aligned).
        const float4* gin4 = (const float4*)(in + row0 * NCOLS);
        float4* s_in4 = (float4*)s_in;
        if (t < (ROWS * NCOLS) / 4) s_in4[t] = gin4[t];   // 252 float4 loads
    } else {
        for (int idx = t; idx < ROWS * NCOLS; idx += BLOCK) {
            size_t g = row0 * NCOLS + (size_t)idx;
            if (g < (size_t)B * NCOLS) s_in[idx] = in[g];
        }
    }
    __syncthreads();

    // ---- Compute out-tile in LDS ----
    const int r = t >> 4;   // 0..15 : local row
    const int l = t & 15;   // 0..15 : lane within row
    const float* rowin  = s_in  + r * NCOLS;
    float*       rowout = s_out + r * OUTCOLS;

    // passthrough columns
    for (int c = l; c < NCOLS; c += 16) rowout[c] = rowin[c];

    // pair features
    for (int p = l; p < NPAIRS; p += 16) {
        const int ia = s_pi[p], ka = s_pk[p];
        const float vx = rowin[ka]     - rowin[ia];
        const float vy = rowin[ka + 1] - rowin[ia + 1];
        const float inv = rsqrtf(vx * vx + vy * vy);
        float tx = vx * inv;
        float ty = vy * inv;
        tx = fminf(fmaxf(tx, -1.0f), 1.0f);
        ty = fminf(fmaxf(ty, -1.0f), 1.0f);
        rowout[NCOLS + 2 * p]     = tx;
        rowout[NCOLS + 2 * p + 1] = ty;
    }
    __syncthreads();

    // ---- Dump out-tile: 7728 contiguous floats, slab byte offset 30912*blockIdx (16B aligned) ----
    if (full) {
        float4* gout4 = (float4*)(out + row0 * OUTCOLS);
        const float4* s_out4 = (const float4*)s_out;
        for (int idx = t; idx < (ROWS * OUTCOLS) / 4; idx += BLOCK)
            gout4[idx] = s_out4[idx];                      // 1932 float4 stores
    } else {
        for (int idx = t; idx < ROWS * OUTCOLS; idx += BLOCK) {
            size_t g = row0 * OUTCOLS + (size_t)idx;
            if (g < (size_t)B * OUTCOLS) out[g] = s_out[idx];
        }
    }
}

extern "C" void kernel_launch(void* const* d_in, const int* in_sizes, int n_in,
                              void* d_out, int out_size, void* d_ws, size_t ws_size,
                              hipStream_t stream) {
    const float* in = (const float*)d_in[0];
    float* out = (float*)d_out;
    const int B = in_sizes[0] / NCOLS;
    const int grid = (B + ROWS - 1) / ROWS;
    hipLaunchKernelGGL(angular_kernel, dim3(grid), dim3(BLOCK), 0, stream, in, out, B);
}